// Round 7
// baseline (128.154 us; speedup 1.0000x reference)
//
#include <hip/hip_runtime.h>

// Species-routed expert Linear as a bucketed grouped GEMM.
//   out[a] = rho[a] @ W[sym[a]] + b[sym[a]]   (NTA=65536, K=N=512, 4 species)
// R7: R6 structure (full A-tile prologue gather -> 64KB LDS, barrier-free
//     K-loop) + NEW EPILOGUE: accumulators are transposed through LDS (2
//     passes x 32 rows, reusing Abuf) so every wave store-instruction writes
//     1 KB CONTIGUOUS of one output row (global_store_dwordx4), replacing the
//     64 scalar scattered half-line stores/thread that R5/R6 showed cost
//     ~60 of the 103 us.

#define NTA   65536
#define DIM_O 512
#define NMAXD 512
#define NSPE  4
#define BM    64
#define BK    64

typedef __attribute__((ext_vector_type(4))) float  f32x4;
typedef __attribute__((ext_vector_type(8))) short  bf16x8;
typedef __attribute__((ext_vector_type(4))) short  bf16x4;

__device__ __forceinline__ short f2bf(float f) {
    unsigned u = __builtin_bit_cast(unsigned, f);
    u += 0x7FFFu + ((u >> 16) & 1u);
    return (short)(u >> 16);
}

// LDS-visibility barrier that does NOT drain vmcnt
__device__ __forceinline__ void bar_lds() {
    asm volatile("s_waitcnt lgkmcnt(0)" ::: "memory");
    __builtin_amdgcn_s_barrier();
    __builtin_amdgcn_sched_barrier(0);
}

__global__ void build_lists_kernel(const int* __restrict__ sym,
                                   int* __restrict__ counts,
                                   int* __restrict__ lists) {
    int i = blockIdx.x * 256 + threadIdx.x;
    int s = sym[i];
    int lane = threadIdx.x & 63;
    #pragma unroll
    for (int spe = 0; spe < NSPE; ++spe) {
        unsigned long long m = __ballot(s == spe);
        if (m == 0ull) continue;
        int leader = __ffsll(m) - 1;
        int base = 0;
        if (lane == leader) base = atomicAdd(&counts[spe], __popcll(m));
        base = __shfl(base, leader);
        if (s == spe) {
            int pos = __popcll(m & ((1ull << lane) - 1ull));
            lists[spe * NTA + base + pos] = i;
        }
    }
}

// Pack W[s][k][n] (fp32) -> bf16 MFMA-B fragment layout; also zeroes counts
// (launched BEFORE build_lists on the same stream).
__global__ void pack_w_kernel(const float* __restrict__ W, short* __restrict__ Wp,
                              int* __restrict__ counts) {
    if (blockIdx.x == 0 && threadIdx.x < NSPE) counts[threadIdx.x] = 0;
    int idx = blockIdx.x * 256 + threadIdx.x;
    int j  = idx & 7;
    int l  = (idx >> 3) & 63;
    int nb = (idx >> 9) & 31;
    int kb = (idx >> 14) & 15;
    int s  = idx >> 18;
    int k = kb * 32 + (l >> 4) * 8 + j;
    int n = nb * 16 + (l & 15);
    Wp[idx] = f2bf(W[((size_t)s * DIM_O + k) * NMAXD + n]);
}

// LDS A layout (full K): 16B slot = chunk*64 + (row ^ ((chunk&3)<<1)),
// chunk = k-floats [8c, 8c+8), c in 0..63. Measured 0 conflicts.
__global__ __launch_bounds__(512, 4)
void gemm_kernel(const float* __restrict__ rho,
                 const short* __restrict__ Wp,
                 const float* __restrict__ bias,
                 const int*  __restrict__ counts,
                 const int*  __restrict__ lists,
                 float* __restrict__ out)
{
    const int s   = blockIdx.x & 3;
    const int mb  = blockIdx.x >> 2;
    const int cnt = counts[s];
    const int row0 = mb * BM;
    if (row0 >= cnt) return;
    int rows_here = cnt - row0; if (rows_here > BM) rows_here = BM;

    __shared__ int aidx[BM];
    __shared__ __align__(16) short Abuf[64 * 64 * 8];   // 64 KB: A tile, then O-transpose

    const int tid  = threadIdx.x;
    const int lane = tid & 63;
    const int w    = tid >> 6;            // wave 0..7 owns cols [w*64, w*64+64)
    const int lrow = lane & 15;
    const int lgr  = lane >> 4;

    if (tid < BM)
        aidx[tid] = lists[s * NTA + row0 + ((tid < rows_here) ? tid : 0)];
    __syncthreads();

    // ---- prologue: gather the WHOLE A tile (once), convert, stage to LDS ----
    {
        const int srow  = tid >> 3;
        const int scol8 = tid & 7;
        const float* gsrc = rho + (size_t)aidx[srow] * DIM_O + scol8 * 4;
        const int c0   = scol8 >> 1;
        const int roww = srow ^ ((c0 & 3) << 1);
        const int dof  = (scol8 & 1) * 4;

        f32x4 v[16];
        #pragma unroll
        for (int r = 0; r < 16; ++r)
            v[r] = *(const f32x4*)(gsrc + r * 32);
        #pragma unroll
        for (int r = 0; r < 16; ++r) {
            bf16x4 a;
            #pragma unroll
            for (int q = 0; q < 4; ++q) a[q] = f2bf(v[r][q]);
            *(bf16x4*)&Abuf[((r * 4 + c0) * 64 + roww) * 8 + dof] = a;
        }
    }
    __syncthreads();

    // ---- barrier-free K-loop: read-only LDS + L2-resident B + MFMA ----
    const short* wbase = Wp + ((size_t)s * 512 + w * 4) * 512 + lane * 8;

    f32x4 acc[4][4];
    #pragma unroll
    for (int m = 0; m < 4; ++m)
        #pragma unroll
        for (int n = 0; n < 4; ++n) acc[m][n] = (f32x4)0.0f;

    #pragma unroll
    for (int kt = 0; kt < 8; ++kt) {
        bf16x8 bfr[2][4];
        #pragma unroll
        for (int ks = 0; ks < 2; ++ks)
            #pragma unroll
            for (int nf = 0; nf < 4; ++nf)
                bfr[ks][nf] = *(const bf16x8*)
                    (wbase + (size_t)((kt * 2 + ks) * 32 + nf) * 512);
        #pragma unroll
        for (int ks = 0; ks < 2; ++ks) {
            #pragma unroll
            for (int mf = 0; mf < 4; ++mf) {
                const int c = kt * 8 + ks * 4 + lgr;
                const int r = (mf * 16 + lrow) ^ ((lgr & 3) << 1);
                const bf16x8 afrag = *(const bf16x8*)&Abuf[(c * 64 + r) * 8];
                #pragma unroll
                for (int nf = 0; nf < 4; ++nf)
                    acc[mf][nf] = __builtin_amdgcn_mfma_f32_16x16x32_bf16(
                        afrag, bfr[ks][nf], acc[mf][nf], 0, 0, 0);
            }
        }
    }

    // ---- epilogue: LDS transpose -> contiguous 1KB-per-instruction stores ----
    float bv[4];
    #pragma unroll
    for (int nf = 0; nf < 4; ++nf)
        bv[nf] = bias[s * NMAXD + w * 64 + nf * 16 + lrow];

    float* Obuf = (float*)Abuf;   // 32 rows x 512 f32 per pass = 64 KB
    bar_lds();                    // all A-tile LDS reads done before overwrite

    #pragma unroll
    for (int p = 0; p < 2; ++p) {
        // write phase: acc rows [p*32, p*32+32); col-XOR by lgr -> 2-way max
        #pragma unroll
        for (int m2 = 0; m2 < 2; ++m2) {
            const int mf = p * 2 + m2;
            #pragma unroll
            for (int q = 0; q < 4; ++q) {
                const int rl = m2 * 16 + lgr * 4 + q;          // 0..31
                const int sw = ((rl >> 2) & 3) << 4;
                #pragma unroll
                for (int nf = 0; nf < 4; ++nf) {
                    const int col = w * 64 + nf * 16 + lrow;
                    Obuf[rl * 512 + (col ^ sw)] = acc[mf][nf][q] + bv[nf];
                }
            }
        }
        bar_lds();
        // read+store phase: wave w stores rows [w*4, w*4+4); 1KB contiguous/instr
        #pragma unroll
        for (int rr = 0; rr < 4; ++rr) {
            const int rl = w * 4 + rr;
            const int gr = p * 32 + rl;
            const int sw = ((rl >> 2) & 3) << 4;
            if (gr < rows_here) {
                float* orow = out + (size_t)aidx[gr] * NMAXD;
                #pragma unroll
                for (int h = 0; h < 2; ++h) {
                    const int cd = h * 256 + lane * 4;
                    f32x4 v = *(const f32x4*)&Obuf[rl * 512 + (cd ^ sw)];
                    *(f32x4*)&orow[cd] = v;
                }
            }
        }
        if (p == 0) bar_lds();
    }
}

extern "C" void kernel_launch(void* const* d_in, const int* in_sizes, int n_in,
                              void* d_out, int out_size, void* d_ws, size_t ws_size,
                              hipStream_t stream) {
    const float* rho = (const float*)d_in[0];
    const float* W   = (const float*)d_in[1];
    const float* b   = (const float*)d_in[2];
    const int*   sym = (const int*)d_in[3];
    float* out = (float*)d_out;

    int*   counts = (int*)d_ws;
    int*   lists  = (int*)((char*)d_ws + 1024);
    short* Wp     = (short*)((char*)d_ws + 1024 + (size_t)NSPE * NTA * 4);

    pack_w_kernel<<<(NSPE * DIM_O * NMAXD) / 256, 256, 0, stream>>>(W, Wp, counts);
    build_lists_kernel<<<NTA / 256, 256, 0, stream>>>(sym, counts, lists);
    gemm_kernel<<<NSPE * (NTA / BM), 512, 0, stream>>>(rho, Wp, b, counts, lists, out);
}